// Round 4
// baseline (19124.683 us; speedup 1.0000x reference)
//
#include <hip/hip_runtime.h>
#include <stdint.h>

#define E    512
#define H    8
#define DH   64
#define BB   8
#define SS   24
#define FF   2048
#define NL   3
#define VTOK 32000
#define LBUF 25
#define ML   24
#define START_ID 1

// Spin-wait timeout in s_memrealtime ticks (~100 MHz => ~0.5 s).
// On timeout we proceed (and still signal) => wrong answer, never a hang.
#define MWAIT_TIMEOUT 50000000ull

// ===========================================================================
// Coherent (agent-scope, L2-bypass) access helpers for cross-block data.
// Weights/read-only data use normal cached loads and are NEVER invalidated.
// ===========================================================================
__device__ __forceinline__ float cld(const float* p) {
  return __hip_atomic_load(p, __ATOMIC_RELAXED, __HIP_MEMORY_SCOPE_AGENT);
}
__device__ __forceinline__ void cst(float* p, float v) {
  __hip_atomic_store(p, v, __ATOMIC_RELAXED, __HIP_MEMORY_SCOPE_AGENT);
}
__device__ __forceinline__ int cldi(const int* p) {
  return __hip_atomic_load(p, __ATOMIC_RELAXED, __HIP_MEMORY_SCOPE_AGENT);
}
__device__ __forceinline__ void csti(int* p, int v) {
  __hip_atomic_store(p, v, __ATOMIC_RELAXED, __HIP_MEMORY_SCOPE_AGENT);
}
__device__ __forceinline__ unsigned long long cldu(const unsigned long long* p) {
  return __hip_atomic_load(p, __ATOMIC_RELAXED, __HIP_MEMORY_SCOPE_AGENT);
}
__device__ __forceinline__ void cstu(unsigned long long* p, unsigned long long v) {
  __hip_atomic_store(p, v, __ATOMIC_RELAXED, __HIP_MEMORY_SCOPE_AGENT);
}

// ===========================================================================
// Encoder-side kernels (host-sequenced; ~40 dispatches total)
// ===========================================================================

__global__ void enc_embed_kernel(const int* __restrict__ inp, const float* __restrict__ emb,
                                 float* __restrict__ x) {
  int r = blockIdx.x;
  int s = r / BB, b = r % BB;
  int tok = inp[b * SS + s];
  const float* er = emb + (size_t)tok * E;
  for (int e = threadIdx.x; e < E; e += blockDim.x) {
    int j = e >> 1;
    double dv = exp(-((double)(2 * j)) * (log(10000.0) / (double)E));
    double ang = (double)s * dv;
    double pe = (e & 1) ? cos(ang) : sin(ang);
    x[(size_t)r * E + e] = er[e] + (float)pe;
  }
}

__global__ __launch_bounds__(256) void ln_kernel(const float* __restrict__ x,
                          const float* __restrict__ g,
                          const float* __restrict__ bta, float* __restrict__ y) {
  int r = blockIdx.x;
  int t = threadIdx.x;
  const float* xr = x + (size_t)r * E;
  float a0 = xr[t], a1 = xr[t + 256];
  __shared__ float red[256];
  red[t] = a0 + a1;
  __syncthreads();
  for (int s = 128; s > 0; s >>= 1) { if (t < s) red[t] += red[t + s]; __syncthreads(); }
  float m = red[0] * (1.0f / (float)E);
  __syncthreads();
  float d0 = a0 - m, d1 = a1 - m;
  red[t] = d0 * d0 + d1 * d1;
  __syncthreads();
  for (int s = 128; s > 0; s >>= 1) { if (t < s) red[t] += red[t + s]; __syncthreads(); }
  float v = red[0] * (1.0f / (float)E);
  float rstd = 1.0f / sqrtf(v + 1e-5f);
  y[(size_t)r * E + t]       = d0 * rstd * g[t]       + bta[t];
  y[(size_t)r * E + t + 256] = d1 * rstd * g[t + 256] + bta[t + 256];
}

__global__ __launch_bounds__(256) void fgemm_kernel(
    const float* __restrict__ A, int K,
    const float* __restrict__ W, int ldw, int N,
    const float* __restrict__ bias,
    const float* __restrict__ resid,
    float* __restrict__ C, int relu) {
  __shared__ float Al[8 * 512];
  __shared__ float red[16 * 512];
  int t = threadIdx.x;
  int c0 = blockIdx.x * 64;
  int s = blockIdx.y;
  int row0 = blockIdx.z * 8;
  int kbase = s * 512;
  for (int i = t; i < 1024; i += 256) {
    int r = i >> 7, cc = i & 127;
    ((float4*)Al)[i] = *(const float4*)(A + (size_t)(row0 + r) * K + kbase + (cc << 2));
  }
  __syncthreads();
  int tc = t & 15, tk = t >> 4;
  int col = c0 + (tc << 2);
  float acc[8][4];
#pragma unroll
  for (int m = 0; m < 8; ++m) { acc[m][0] = acc[m][1] = acc[m][2] = acc[m][3] = 0.f; }
  const float4* wp = (const float4*)(W + (size_t)kbase * ldw + col);
  const size_t ld4 = (size_t)(ldw >> 2);
#pragma unroll 8
  for (int i = 0; i < 32; ++i) {
    int k = tk + (i << 4);
    float4 wv = wp[(size_t)k * ld4];
#pragma unroll
    for (int m = 0; m < 8; ++m) {
      float a = Al[m * 512 + k];
      acc[m][0] += a * wv.x; acc[m][1] += a * wv.y;
      acc[m][2] += a * wv.z; acc[m][3] += a * wv.w;
    }
  }
#pragma unroll
  for (int m = 0; m < 8; ++m) {
    float4* rr = (float4*)&red[tk * 512 + m * 64 + (tc << 2)];
    *rr = make_float4(acc[m][0], acc[m][1], acc[m][2], acc[m][3]);
  }
  __syncthreads();
  float out2[2];
#pragma unroll
  for (int j = 0; j < 2; ++j) {
    int o = t + j * 256;
    float v = 0.f;
#pragma unroll
    for (int sl = 0; sl < 16; ++sl) v += red[sl * 512 + o];
    out2[j] = v;
  }
  int S = gridDim.y;
  if (S > 1) {
    int M = gridDim.z * 8;
#pragma unroll
    for (int j = 0; j < 2; ++j) {
      int o = t + j * 256; int m = o >> 6, cc = o & 63;
      C[((size_t)s * M + row0 + m) * N + c0 + cc] = out2[j];
    }
  } else {
#pragma unroll
    for (int j = 0; j < 2; ++j) {
      int o = t + j * 256; int m = o >> 6, cc = o & 63;
      int col2 = c0 + cc;
      float v = out2[j] + bias[col2];
      if (resid) v += resid[(size_t)(row0 + m) * N + col2];
      if (relu) v = fmaxf(v, 0.0f);
      C[(size_t)(row0 + m) * N + col2] = v;
    }
  }
}

__global__ __launch_bounds__(256) void reduce_br_kernel(const float* __restrict__ part, int S, int M,
                                 const float* __restrict__ bias,
                                 const float* __restrict__ resid,
                                 float* __restrict__ outp) {
  int r = blockIdx.x, t = threadIdx.x;
#pragma unroll
  for (int j = 0; j < 2; ++j) {
    int c = t + j * 256;
    float v = bias[c] + resid[(size_t)r * E + c];
    for (int s = 0; s < S; ++s) v += part[((size_t)s * M + r) * E + c];
    outp[(size_t)r * E + c] = v;
  }
}

__global__ void enc_attn_kernel(const float* __restrict__ qkv, float* __restrict__ o) {
  int b = blockIdx.x >> 3, h = blockIdx.x & 7;
  __shared__ float qs[SS * DH], ks[SS * DH], vs[SS * DH];
  __shared__ float sc[SS][SS];
  int t = threadIdx.x;
  for (int idx = t; idx < SS * DH; idx += 256) {
    int srow = idx / DH, d = idx - srow * DH;
    size_t base = ((size_t)(srow * BB + b)) * (3 * E) + h * DH + d;
    qs[idx] = qkv[base];
    ks[idx] = qkv[base + E];
    vs[idx] = qkv[base + 2 * E];
  }
  __syncthreads();
  for (int p = t; p < SS * SS; p += 256) {
    int qi = p / SS, kj = p - qi * SS;
    float a = 0.f;
    for (int d = 0; d < DH; ++d) a += qs[qi * DH + d] * ks[kj * DH + d];
    sc[qi][kj] = a * 0.125f;
  }
  __syncthreads();
  if (t < SS) {
    float mx = -1e30f;
    for (int j = 0; j < SS; ++j) mx = fmaxf(mx, sc[t][j]);
    float sm = 0.f;
    for (int j = 0; j < SS; ++j) { float ev = expf(sc[t][j] - mx); sc[t][j] = ev; sm += ev; }
    float inv = 1.0f / sm;
    for (int j = 0; j < SS; ++j) sc[t][j] *= inv;
  }
  __syncthreads();
  for (int p = t; p < SS * DH; p += 256) {
    int qi = p / DH, d = p - qi * DH;
    float a = 0.f;
    for (int j = 0; j < SS; ++j) a += sc[qi][j] * vs[j * DH + d];
    o[((size_t)(qi * BB + b)) * E + h * DH + d] = a;
  }
}

// ===========================================================================
// Persistent decode megakernel — lightweight coherent-dataflow barriers.
//   * no __threadfence (no buffer_inv / buffer_wbl2 -> L2 stays warm)
//   * intermediates: agent-scope relaxed atomics (write-through)
//   * weights: normal cached loads (read-only, never stale)
//   * KV cache: coherent write-once, cached reads (each line written before
//     any reader ever caches it; graph replays recompute identical values,
//     so residual stale lines are value-identical => benign)
//   * HANG-PROOF: bounded spins; on timeout a block proceeds AND signals,
//     so worst case is a fast wrong answer, never a stuck container.
// ===========================================================================

struct DecP {
  const float* emb;
  const float* saw; const float* sab; const float* saow; const float* saob;
  const float* caw; const float* cab; const float* caow; const float* caob;
  const float* l1g; const float* l1b; const float* l2g; const float* l2b;
  const float* l3g; const float* l3b;
  const float* f1w; const float* f1b; const float* f2w; const float* f2b;
  const float* ng; const float* nb; const float* vw; const float* vb;
  const float* mem_k; const float* mem_v;
  float* dqkv; float* y_in; float* y1; float* y1raw; float* qca;
  float* y2; float* y2raw; float* dmid; float* partD;
  float* cacheK; float* cacheV; float* out;
  unsigned long long* vmax; int* tokens; int* pd; int* arr;
};

__device__ inline void mwait(int* pd, int target) {
  __syncthreads();
  if (threadIdx.x == 0) {
    unsigned long long t0 = __builtin_amdgcn_s_memrealtime();
    for (;;) {
      int cur = __hip_atomic_load(pd, __ATOMIC_RELAXED, __HIP_MEMORY_SCOPE_AGENT);
      if (cur >= target) break;
      int d = target - cur;
      if (d > 2) __builtin_amdgcn_s_sleep(64);
      else       __builtin_amdgcn_s_sleep(1);
      if (__builtin_amdgcn_s_memrealtime() - t0 > MWAIT_TIMEOUT) break;  // hang-proof
    }
  }
  __syncthreads();   // block-wide ordering; consumers use coherent loads
}

__device__ inline void msignal(int* arr, int* pd, int phidx, int nprod) {
  // EVERY wave drains its own outstanding stores (vmcnt is per-wave) so the
  // phase's data is at the coherent point before the last arriver signals.
  asm volatile("s_waitcnt vmcnt(0)" ::: "memory");
  __syncthreads();
  if (threadIdx.x == 0) {
    int a = __hip_atomic_fetch_add(&arr[phidx], 1, __ATOMIC_RELAXED, __HIP_MEMORY_SCOPE_AGENT);
    if (a + 1 == nprod)
      __hip_atomic_fetch_add(pd, 1, __ATOMIC_RELAXED, __HIP_MEMORY_SCOPE_AGENT);
  }
}

__device__ inline void ln_lds(float* Al, const float* __restrict__ g,
                              const float* __restrict__ b, float* rm, float* rrs) {
  int t = threadIdx.x;
  int rr = t >> 5, q = t & 31;
  const float* ar = Al + rr * 512;
  float sm = 0.f, s2 = 0.f;
  for (int j = q; j < 512; j += 32) { float v = ar[j]; sm += v; s2 += v * v; }
  for (int off = 16; off; off >>= 1) {
    sm += __shfl_down(sm, off, 32);
    s2 += __shfl_down(s2, off, 32);
  }
  if (q == 0) {
    float m = sm * (1.0f / 512.0f);
    float var = s2 * (1.0f / 512.0f) - m * m;
    rm[rr] = m;
    rrs[rr] = 1.0f / sqrtf(var + 1e-5f);
  }
  __syncthreads();
  for (int idx = t; idx < 4096; idx += 256) {
    int r2 = idx >> 9, c2 = idx & 511;
    Al[idx] = (Al[idx] - rm[r2]) * rrs[r2] * g[c2] + b[c2];
  }
  __syncthreads();
}

__device__ inline void gemm_slice(const float* __restrict__ W, size_t ldw, int col0,
                                  const float* Al, float* red, float out2[2]) {
  int t = threadIdx.x;
  __syncthreads();
  int tc = t & 15, tk = t >> 4;
  float acc[8][4];
#pragma unroll
  for (int m = 0; m < 8; ++m) { acc[m][0] = acc[m][1] = acc[m][2] = acc[m][3] = 0.f; }
  const float4* wp = (const float4*)(W + col0 + (tc << 2));
  const size_t ld4 = ldw >> 2;
#pragma unroll 8
  for (int i = 0; i < 32; ++i) {
    int k = tk + (i << 4);
    float4 wv = wp[(size_t)k * ld4];
#pragma unroll
    for (int m = 0; m < 8; ++m) {
      float a = Al[m * 512 + k];
      acc[m][0] += a * wv.x; acc[m][1] += a * wv.y;
      acc[m][2] += a * wv.z; acc[m][3] += a * wv.w;
    }
  }
#pragma unroll
  for (int m = 0; m < 8; ++m) {
    float4* rr = (float4*)&red[tk * 512 + m * 64 + (tc << 2)];
    *rr = make_float4(acc[m][0], acc[m][1], acc[m][2], acc[m][3]);
  }
  __syncthreads();
#pragma unroll
  for (int j = 0; j < 2; ++j) {
    int o = t + j * 256;
    float v = 0.f;
#pragma unroll
    for (int sl = 0; sl < 16; ++sl) v += red[sl * 512 + o];
    out2[j] = v;
  }
}

__global__ __launch_bounds__(256) void decode_mega(DecP P) {
  __shared__ float Al[8 * 512];                 // 16 KB
  __shared__ float red[16 * 512];               // 32 KB
  __shared__ float sc[64][25];                  // 6.25 KB
  __shared__ float rm[8], rrs[8];
  __shared__ unsigned long long rowmax[8];
  __shared__ int toks[8];
  const int bid = blockIdx.x, t = threadIdx.x;
  int* pd = P.pd; int* arr = P.arr;
  int ph = 0;

  // ---- phase 0: init tokens (block 0) ----
  if (bid == 0) {
    mwait(pd, ph);
    if (t < BB) csti(&P.tokens[t], START_ID);
    msignal(arr, pd, ph, 1);
  }
  ++ph;

  for (int i = 0; i < ML; ++i) {
    for (int l = 0; l < NL; ++l) {
      const float* saw_l  = P.saw  + (size_t)l * E * 3 * E;
      const float* sab_l  = P.sab  + (size_t)l * 3 * E;
      const float* saow_l = P.saow + (size_t)l * E * E;
      const float* saob_l = P.saob + (size_t)l * E;
      const float* caw_l  = P.caw  + (size_t)l * E * 3 * E;
      const float* cab_l  = P.cab  + (size_t)l * 3 * E;
      const float* caow_l = P.caow + (size_t)l * E * E;
      const float* caob_l = P.caob + (size_t)l * E;
      const float* f1w_l  = P.f1w  + (size_t)l * E * FF;
      const float* f1b_l  = P.f1b  + (size_t)l * FF;
      const float* f2w_l  = P.f2w  + (size_t)l * FF * E;
      float* Kc = P.cacheK + (size_t)l * LBUF * BB * E;
      float* Vc = P.cacheV + (size_t)l * LBUF * BB * E;
      const float* Km = P.mem_k + (size_t)l * 192 * E;
      const float* Vm = P.mem_v + (size_t)l * 192 * E;

      // ---- P1: QKV projection (24 blocks) ----
      if (bid < 24) {
        mwait(pd, ph);
        if (l == 0) {
          if (t < BB) toks[t] = cldi(&P.tokens[(size_t)i * BB + t]);
          __syncthreads();
          for (int idx = t; idx < 4096; idx += 256) {
            int r = idx >> 9, c = idx & 511;
            Al[idx] = P.emb[(size_t)toks[r] * E + c];   // cached (read-only)
          }
          __syncthreads();
        } else {
          const float* f2b_p = P.f2b + (size_t)(l - 1) * E;
          for (int idx = t; idx < 4096; idx += 256) {
            int r = idx >> 9, c = idx & 511;
            float v = f2b_p[c] + cld(&P.y2[(size_t)r * E + c]);
#pragma unroll
            for (int sl = 0; sl < 4; ++sl)
              v += cld(&P.partD[((size_t)sl * 8 + r) * E + c]);
            Al[idx] = v;
          }
          __syncthreads();
          ln_lds(Al, P.l3g + (size_t)(l - 1) * E, P.l3b + (size_t)(l - 1) * E, rm, rrs);
        }
        if (bid == 0) for (int idx = t; idx < 4096; idx += 256) cst(&P.y_in[idx], Al[idx]);
        float out2[2];
        gemm_slice(saw_l, 3 * E, bid * 64, Al, red, out2);
#pragma unroll
        for (int j = 0; j < 2; ++j) {
          int o = t + j * 256; int m = o >> 6, cc = o & 63;
          int col2 = bid * 64 + cc;
          cst(&P.dqkv[(size_t)m * (3 * E) + col2], out2[j] + sab_l[col2]);
        }
        msignal(arr, pd, ph, 24);
      }
      ++ph;

      // ---- P2: self-attn + out-proj + resid (8 blocks) ----
      if (bid < 8) {
        mwait(pd, ph);
        // Stage q -> Al, K_i -> red[0..4095], V_i -> red[4096..8191]
        for (int idx = t; idx < 4096; idx += 256) {
          int b = idx >> 9, e = idx & 511;
          const float* row = P.dqkv + (size_t)b * 1536;
          Al[idx]         = cld(row + e);
          red[idx]        = cld(row + 512 + e);
          red[4096 + idx] = cld(row + 1024 + e);
        }
        __syncthreads();
        if (bid == 0) {
          for (int idx = t; idx < 4096; idx += 256) {
            int b = idx >> 9, e = idx & 511;
            cst(&Kc[((size_t)i * BB + b) * E + e], red[idx]);
            cst(&Vc[((size_t)i * BB + b) * E + e], red[4096 + idx]);
          }
        }
        int L = i + 1;
        {
          int pr = t >> 2, q = t & 3;
          int b = pr >> 3, h = pr & 7;
          const float* qs = Al + b * 512 + h * 64;
          for (int j = q; j < L; j += 4) {
            float a = 0.f;
            if (j == i) {
              const float* kr = red + b * 512 + h * 64;
#pragma unroll 16
              for (int d = 0; d < 64; ++d) a += qs[d] * kr[d];
            } else {
              const float4* k4 = (const float4*)(Kc + ((size_t)j * BB + b) * E + h * 64);
#pragma unroll
              for (int d = 0; d < 16; ++d) {
                float4 kv = k4[d];   // cached: write-once line, written before first read
                a += qs[d*4+0]*kv.x + qs[d*4+1]*kv.y + qs[d*4+2]*kv.z + qs[d*4+3]*kv.w;
              }
            }
            sc[pr][j] = a * 0.125f;
          }
        }
        __syncthreads();
        if ((t & 3) == 0) {
          int pr = t >> 2;
          float mx = -1e30f;
          for (int j = 0; j < L; ++j) mx = fmaxf(mx, sc[pr][j]);
          float sm = 0.f;
          for (int j = 0; j < L; ++j) { float ev = expf(sc[pr][j] - mx); sc[pr][j] = ev; sm += ev; }
          float inv = 1.0f / sm;
          for (int j = 0; j < L; ++j) sc[pr][j] *= inv;
        }
        __syncthreads();
        for (int ii = 0; ii < 16; ++ii) {
          int idx = t + (ii << 8);
          int b = idx >> 9, e = idx & 511, h = e >> 6;
          int pr = b * 8 + h;
          float a = sc[pr][i] * red[4096 + b * 512 + e];     // j == i from LDS
          for (int j = 0; j < i; ++j)
            a += sc[pr][j] * Vc[((size_t)j * BB + b) * E + e];   // cached
          Al[idx] = a;
        }
        float out2[2];
        gemm_slice(saow_l, E, bid * 64, Al, red, out2);
#pragma unroll
        for (int j = 0; j < 2; ++j) {
          int o = t + j * 256; int m = o >> 6, cc = o & 63;
          int col2 = bid * 64 + cc;
          cst(&P.y1raw[(size_t)m * E + col2],
              out2[j] + saob_l[col2] + cld(&P.y_in[(size_t)m * E + col2]));
        }
        msignal(arr, pd, ph, 8);
      }
      ++ph;

      // ---- P3: LN1 + cross-attn q projection (8 blocks) ----
      if (bid < 8) {
        mwait(pd, ph);
        for (int idx = t; idx < 4096; idx += 256)
          Al[idx] = cld(&P.y1raw[idx]);
        __syncthreads();
        ln_lds(Al, P.l1g + (size_t)l * E, P.l1b + (size_t)l * E, rm, rrs);
        if (bid == 0) for (int idx = t; idx < 4096; idx += 256) cst(&P.y1[idx], Al[idx]);
        float out2[2];
        gemm_slice(caw_l, 3 * E, bid * 64, Al, red, out2);
#pragma unroll
        for (int j = 0; j < 2; ++j) {
          int o = t + j * 256; int m = o >> 6, cc = o & 63;
          int col2 = bid * 64 + cc;
          cst(&P.qca[(size_t)m * E + col2], out2[j] + cab_l[col2]);
        }
        msignal(arr, pd, ph, 8);
      }
      ++ph;

      // ---- P4: cross-attn + out-proj + resid (8 blocks) ----
      if (bid < 8) {
        mwait(pd, ph);
        for (int idx = t; idx < 4096; idx += 256)
          Al[idx] = cld(&P.qca[idx]);
        __syncthreads();
        {
          int pr = t >> 2, q = t & 3;
          int b = pr >> 3, h = pr & 7;
          const float* qs = Al + b * 512 + h * 64;
          for (int j = q; j < SS; j += 4) {
            const float4* k4 = (const float4*)(Km + ((size_t)j * BB + b) * E + h * 64);
            float a = 0.f;
#pragma unroll
            for (int d = 0; d < 16; ++d) {
              float4 kv = k4[d];   // cached (written before mega launch)
              a += qs[d*4+0]*kv.x + qs[d*4+1]*kv.y + qs[d*4+2]*kv.z + qs[d*4+3]*kv.w;
            }
            sc[pr][j] = a * 0.125f;
          }
        }
        __syncthreads();
        if ((t & 3) == 0) {
          int pr = t >> 2;
          float mx = -1e30f;
          for (int j = 0; j < SS; ++j) mx = fmaxf(mx, sc[pr][j]);
          float sm = 0.f;
          for (int j = 0; j < SS; ++j) { float ev = expf(sc[pr][j] - mx); sc[pr][j] = ev; sm += ev; }
          float inv = 1.0f / sm;
          for (int j = 0; j < SS; ++j) sc[pr][j] *= inv;
        }
        __syncthreads();
        for (int ii = 0; ii < 16; ++ii) {
          int idx = t + (ii << 8);
          int b = idx >> 9, e = idx & 511, h = e >> 6;
          int pr = b * 8 + h;
          float a = 0.f;
          for (int j = 0; j < SS; ++j)
            a += sc[pr][j] * Vm[((size_t)j * BB + b) * E + e];   // cached
          Al[idx] = a;
        }
        float out2[2];
        gemm_slice(caow_l, E, bid * 64, Al, red, out2);
#pragma unroll
        for (int j = 0; j < 2; ++j) {
          int o = t + j * 256; int m = o >> 6, cc = o & 63;
          int col2 = bid * 64 + cc;
          cst(&P.y2raw[(size_t)m * E + col2],
              out2[j] + caob_l[col2] + cld(&P.y1[(size_t)m * E + col2]));
        }
        msignal(arr, pd, ph, 8);
      }
      ++ph;

      // ---- P5: LN2 + FFN1 + relu (32 blocks) ----
      if (bid < 32) {
        mwait(pd, ph);
        for (int idx = t; idx < 4096; idx += 256)
          Al[idx] = cld(&P.y2raw[idx]);
        __syncthreads();
        ln_lds(Al, P.l2g + (size_t)l * E, P.l2b + (size_t)l * E, rm, rrs);
        if (bid == 0) for (int idx = t; idx < 4096; idx += 256) cst(&P.y2[idx], Al[idx]);
        float out2[2];
        gemm_slice(f1w_l, FF, bid * 64, Al, red, out2);
#pragma unroll
        for (int j = 0; j < 2; ++j) {
          int o = t + j * 256; int m = o >> 6, cc = o & 63;
          int col2 = bid * 64 + cc;
          cst(&P.dmid[(size_t)m * FF + col2], fmaxf(out2[j] + f1b_l[col2], 0.0f));
        }
        msignal(arr, pd, ph, 32);
      }
      ++ph;

      // ---- P6: FFN2 k-split partials (32 blocks: 8 col-tiles x 4 k-slices) ----
      if (bid < 32) {
        mwait(pd, ph);
        int ct = bid & 7, ks = bid >> 3;
        int kbase = ks * 512;
        for (int idx = t; idx < 4096; idx += 256) {
          int r = idx >> 9, c = idx & 511;
          Al[idx] = cld(&P.dmid[(size_t)r * FF + kbase + c]);
        }
        float out2[2];
        gemm_slice(f2w_l + (size_t)kbase * E, E, ct * 64, Al, red, out2);
#pragma unroll
        for (int j = 0; j < 2; ++j) {
          int o = t + j * 256; int m = o >> 6, cc = o & 63;
          cst(&P.partD[((size_t)ks * 8 + m) * E + ct * 64 + cc], out2[j]);
        }
        msignal(arr, pd, ph, 32);
      }
      ++ph;
    }

    // ---- P7: vocab GEMM (256 blocks); prologue = FFN2 reduce + LN3 + final LN ----
    {
      mwait(pd, ph);
      const float* f2b_p = P.f2b + (size_t)(NL - 1) * E;
      for (int idx = t; idx < 4096; idx += 256) {
        int r = idx >> 9, c = idx & 511;
        float v = f2b_p[c] + cld(&P.y2[(size_t)r * E + c]);
#pragma unroll
        for (int sl = 0; sl < 4; ++sl)
          v += cld(&P.partD[((size_t)sl * 8 + r) * E + c]);
        Al[idx] = v;
      }
      __syncthreads();
      ln_lds(Al, P.l3g + (size_t)(NL - 1) * E, P.l3b + (size_t)(NL - 1) * E, rm, rrs);
      ln_lds(Al, P.ng, P.nb, rm, rrs);
      if (t < 8) rowmax[t] = 0ull;
      __syncthreads();
      float* dist = P.out + 192 + (size_t)i * (8 * VTOK);
      for (int tt = 0; tt < 2; ++tt) {
        int tile = bid + tt * 256;
        if (tile >= 500) break;
        int col0 = tile * 64;
        float out2[2];
        gemm_slice(P.vw, VTOK, col0, Al, red, out2);
#pragma unroll
        for (int j = 0; j < 2; ++j) {
          int o = t + j * 256; int m = o >> 6, cc = o & 63;
          int col2 = col0 + cc;
          float v = out2[j] + P.vb[col2];
          dist[(size_t)m * VTOK + col2] = v;   // normal store; host-visible at kernel end
          out2[j] = v;
        }
        __syncthreads();
        unsigned long long* keys = (unsigned long long*)red;
#pragma unroll
        for (int j = 0; j < 2; ++j) {
          int o = t + j * 256;
          unsigned int fb = __float_as_uint(out2[j]);
          fb = (fb & 0x80000000u) ? ~fb : (fb | 0x80000000u);
          int col2 = col0 + (o & 63);
          keys[o] = ((unsigned long long)fb << 32) |
                    (unsigned long long)(0xFFFFFFFFu - (unsigned)col2);
        }
        __syncthreads();
        if (t < 64) {
          for (int m = 0; m < 8; ++m) {
            unsigned long long k = keys[m * 64 + t];
            for (int off = 32; off; off >>= 1) {
              unsigned long long o2 = __shfl_down(k, off);
              if (o2 > k) k = o2;
            }
            if (t == 0 && k > rowmax[m]) rowmax[m] = k;
          }
        }
        __syncthreads();
      }
      if (t < 8) cstu(&P.vmax[(size_t)bid * 8 + t], rowmax[t]);
      msignal(arr, pd, ph, 256);
    }
    ++ph;

    // ---- P8: argmax reduce + emit tokens (block 0) ----
    if (bid == 0) {
      mwait(pd, ph);
      unsigned long long* redu = (unsigned long long*)red;
      for (int r = 0; r < 8; ++r) {
        redu[t] = cldu(&P.vmax[(size_t)t * 8 + r]);
        __syncthreads();
        for (int s = 128; s > 0; s >>= 1) {
          if (t < s) { if (redu[t + s] > redu[t]) redu[t] = redu[t + s]; }
          __syncthreads();
        }
        if (t == 0) {
          unsigned int idx = 0xFFFFFFFFu - (unsigned int)(redu[0] & 0xFFFFFFFFull);
          csti(&P.tokens[(size_t)(i + 1) * BB + r], (int)idx);
          P.out[(size_t)i * BB + r] = (float)idx;   // normal store (host-read only)
        }
        __syncthreads();
      }
      msignal(arr, pd, ph, 1);
    }
    ++ph;
  }
}

// ===========================================================================
extern "C" void kernel_launch(void* const* d_in, const int* in_sizes, int n_in,
                              void* d_out, int out_size, void* d_ws, size_t ws_size,
                              hipStream_t stream) {
  (void)in_sizes; (void)n_in; (void)out_size; (void)ws_size;
  const int*   inp   = (const int*)d_in[0];
  const float* emb   = (const float*)d_in[1];
  const float* e_aw  = (const float*)d_in[2];
  const float* e_ab  = (const float*)d_in[3];
  const float* e_aow = (const float*)d_in[4];
  const float* e_aob = (const float*)d_in[5];
  const float* e_l1g = (const float*)d_in[6];
  const float* e_l1b = (const float*)d_in[7];
  const float* e_l2g = (const float*)d_in[8];
  const float* e_l2b = (const float*)d_in[9];
  const float* e_f1w = (const float*)d_in[10];
  const float* e_f1b = (const float*)d_in[11];
  const float* e_f2w = (const float*)d_in[12];
  const float* e_f2b = (const float*)d_in[13];
  const float* e_ng  = (const float*)d_in[14];
  const float* e_nb  = (const float*)d_in[15];
  const float* d_saw = (const float*)d_in[16];
  const float* d_sab = (const float*)d_in[17];
  const float* d_saow= (const float*)d_in[18];
  const float* d_saob= (const float*)d_in[19];
  const float* d_caw = (const float*)d_in[20];
  const float* d_cab = (const float*)d_in[21];
  const float* d_caow= (const float*)d_in[22];
  const float* d_caob= (const float*)d_in[23];
  const float* d_l1g = (const float*)d_in[24];
  const float* d_l1b = (const float*)d_in[25];
  const float* d_l2g = (const float*)d_in[26];
  const float* d_l2b = (const float*)d_in[27];
  const float* d_l3g = (const float*)d_in[28];
  const float* d_l3b = (const float*)d_in[29];
  const float* d_f1w = (const float*)d_in[30];
  const float* d_f1b = (const float*)d_in[31];
  const float* d_f2w = (const float*)d_in[32];
  const float* d_f2b = (const float*)d_in[33];
  const float* d_ng  = (const float*)d_in[34];
  const float* d_nb  = (const float*)d_in[35];
  const float* voc_w = (const float*)d_in[36];
  const float* voc_b = (const float*)d_in[37];
  float* out = (float*)d_out;

  float* p = (float*)d_ws;
  auto alloc = [&](size_t n) { float* r = p; p += n; return r; };
  float* enc_x   = alloc(192 * 512);
  float* enc_tmp = alloc(192 * 2048);
  float* enc_ao  = alloc(192 * 512);
  float* enc_raw = alloc(192 * 512);
  float* memry   = alloc(192 * 512);
  float* mem_k   = alloc(3 * 192 * 512);
  float* mem_v   = alloc(3 * 192 * 512);
  float* partE   = alloc(4 * 192 * 512);
  float* dqkv    = alloc(8 * 1536);
  float* y_in    = alloc(8 * 512);
  float* y1      = alloc(8 * 512);
  float* y1raw   = alloc(8 * 512);
  float* qca     = alloc(8 * 512);
  float* y2      = alloc(8 * 512);
  float* y2raw   = alloc(8 * 512);
  float* dmid    = alloc(8 * 2048);
  float* partD   = alloc(4 * 8 * 512);
  float* cacheK  = alloc(3 * LBUF * 8 * 512);
  float* cacheV  = alloc(3 * LBUF * 8 * 512);
  int* tokens    = (int*)alloc(256);
  unsigned long long* vmax = (unsigned long long*)alloc(4096);
  int* syncmem   = (int*)alloc(2048);

  int* pd  = syncmem;
  int* arr = syncmem + 64;

  // ---------------- encoder (host-sequenced) ----------------
  enc_embed_kernel<<<dim3(192), dim3(256), 0, stream>>>(inp, emb, enc_x);
  for (int l = 0; l < NL; ++l) {
    const float* w  = e_aw  + (size_t)l * E * 3 * E;
    const float* bq = e_ab  + (size_t)l * 3 * E;
    fgemm_kernel<<<dim3(24, 1, 24), dim3(256), 0, stream>>>(
        enc_x, E, w, 3 * E, 3 * E, bq, nullptr, enc_tmp, 0);
    enc_attn_kernel<<<dim3(64), dim3(256), 0, stream>>>(enc_tmp, enc_ao);
    fgemm_kernel<<<dim3(8, 1, 24), dim3(256), 0, stream>>>(
        enc_ao, E, e_aow + (size_t)l * E * E, E, E, e_aob + (size_t)l * E,
        enc_x, enc_raw, 0);
    ln_kernel<<<dim3(192), dim3(256), 0, stream>>>(enc_raw, e_l1g + l * E, e_l1b + l * E, enc_x);
    fgemm_kernel<<<dim3(32, 1, 24), dim3(256), 0, stream>>>(
        enc_x, E, e_f1w + (size_t)l * E * FF, FF, FF, e_f1b + (size_t)l * FF,
        nullptr, enc_tmp, 1);
    fgemm_kernel<<<dim3(8, 4, 24), dim3(256), 0, stream>>>(
        enc_tmp, FF, e_f2w + (size_t)l * FF * E, E, E, nullptr,
        nullptr, partE, 0);
    reduce_br_kernel<<<dim3(192), dim3(256), 0, stream>>>(
        partE, 4, 192, e_f2b + (size_t)l * E, enc_x, enc_raw);
    ln_kernel<<<dim3(192), dim3(256), 0, stream>>>(enc_raw, e_l2g + l * E, e_l2b + l * E, enc_x);
  }
  ln_kernel<<<dim3(192), dim3(256), 0, stream>>>(enc_x, e_ng, e_nb, memry);

  for (int l = 0; l < NL; ++l) {
    const float* w  = d_caw + (size_t)l * E * 3 * E;
    const float* bq = d_cab + (size_t)l * 3 * E;
    fgemm_kernel<<<dim3(8, 1, 24), dim3(256), 0, stream>>>(
        memry, E, w + E, 3 * E, E, bq + E, nullptr, mem_k + (size_t)l * 192 * 512, 0);
    fgemm_kernel<<<dim3(8, 1, 24), dim3(256), 0, stream>>>(
        memry, E, w + 2 * E, 3 * E, E, bq + 2 * E, nullptr, mem_v + (size_t)l * 192 * 512, 0);
  }

  // ---------------- decode: ONE persistent kernel ----------------
  hipMemsetAsync(syncmem, 0, 2048 * sizeof(int), stream);

  DecP P;
  P.emb = emb;
  P.saw = d_saw; P.sab = d_sab; P.saow = d_saow; P.saob = d_saob;
  P.caw = d_caw; P.cab = d_cab; P.caow = d_caow; P.caob = d_caob;
  P.l1g = d_l1g; P.l1b = d_l1b; P.l2g = d_l2g; P.l2b = d_l2b;
  P.l3g = d_l3g; P.l3b = d_l3b;
  P.f1w = d_f1w; P.f1b = d_f1b; P.f2w = d_f2w; P.f2b = d_f2b;
  P.ng = d_ng; P.nb = d_nb; P.vw = voc_w; P.vb = voc_b;
  P.mem_k = mem_k; P.mem_v = mem_v;
  P.dqkv = dqkv; P.y_in = y_in; P.y1 = y1; P.y1raw = y1raw; P.qca = qca;
  P.y2 = y2; P.y2raw = y2raw; P.dmid = dmid; P.partD = partD;
  P.cacheK = cacheK; P.cacheV = cacheV; P.out = out;
  P.vmax = vmax; P.tokens = tokens; P.pd = pd; P.arr = arr;

  decode_mega<<<dim3(256), dim3(256), 0, stream>>>(P);
}

// Round 5
// 8887.007 us; speedup vs baseline: 2.1520x; 2.1520x over previous
//
#include <hip/hip_runtime.h>
#include <stdint.h>

#define E    512
#define H    8
#define DH   64
#define BB   8
#define SS   24
#define FF   2048
#define NL   3
#define VTOK 32000
#define LBUF 25
#define ML   24
#define START_ID 1

// ---------------------------------------------------------------------------
// Encoder embedding + sinusoidal PE (double to match numpy)
// ---------------------------------------------------------------------------
__global__ void enc_embed_kernel(const int* __restrict__ inp, const float* __restrict__ emb,
                                 float* __restrict__ x) {
  int r = blockIdx.x;
  int s = r / BB, b = r % BB;
  int tok = inp[b * SS + s];
  const float* er = emb + (size_t)tok * E;
  for (int e = threadIdx.x; e < E; e += blockDim.x) {
    int j = e >> 1;
    double dv = exp(-((double)(2 * j)) * (log(10000.0) / (double)E));
    double ang = (double)s * dv;
    double pe = (e & 1) ? cos(ang) : sin(ang);
    x[(size_t)r * E + e] = er[e] + (float)pe;
  }
}

// ---------------------------------------------------------------------------
// Row LayerNorm: grid = rows, block = 256
// ---------------------------------------------------------------------------
__global__ __launch_bounds__(256) void ln_kernel(const float* __restrict__ x,
                          const float* __restrict__ g,
                          const float* __restrict__ bta, float* __restrict__ y) {
  int r = blockIdx.x;
  int t = threadIdx.x;
  const float* xr = x + (size_t)r * E;
  float a0 = xr[t], a1 = xr[t + 256];
  __shared__ float red[256];
  red[t] = a0 + a1;
  __syncthreads();
  for (int s = 128; s > 0; s >>= 1) { if (t < s) red[t] += red[t + s]; __syncthreads(); }
  float m = red[0] * (1.0f / (float)E);
  __syncthreads();
  float d0 = a0 - m, d1 = a1 - m;
  red[t] = d0 * d0 + d1 * d1;
  __syncthreads();
  for (int s = 128; s > 0; s >>= 1) { if (t < s) red[t] += red[t + s]; __syncthreads(); }
  float v = red[0] * (1.0f / (float)E);
  float rstd = 1.0f / sqrtf(v + 1e-5f);
  y[(size_t)r * E + t]       = d0 * rstd * g[t]       + bta[t];
  y[(size_t)r * E + t + 256] = d1 * rstd * g[t + 256] + bta[t + 256];
}

// ---------------------------------------------------------------------------
// Fast GEMM: C[M,N] = A[M,K] @ W[K,N(ldw)] (+bias,resid,relu / or partials)
// grid (N/64, S, M/8), block 256.
// A-source modes (decode fusion):
//   gtok  != null : A rows gathered from gemb via token ids (embed fusion)
//   rpart != null : A = rbias + rresid + sum_{s<4} rpart[s]  (FFN2 reduce fusion)
//   else          : A loaded from A[M,K] at kbase
// lng != null : per-row LayerNorm of the (full 8x512) A tile in LDS prologue
// astore      : block(0,0) writes the final A tile (post-LN) to global
// ---------------------------------------------------------------------------
__global__ __launch_bounds__(256) void fgemm_kernel(
    const float* __restrict__ A, int K,
    const float* __restrict__ W, int ldw, int N,
    const float* __restrict__ bias,
    const float* __restrict__ resid,
    float* __restrict__ C, int relu,
    unsigned long long* __restrict__ amax,
    const float* __restrict__ lng, const float* __restrict__ lnb,
    float* __restrict__ astore,
    const int* __restrict__ gtok, const float* __restrict__ gemb,
    const float* __restrict__ rpart, const float* __restrict__ rbias,
    const float* __restrict__ rresid) {
  __shared__ float Al[8 * 512];      // 16 KB
  __shared__ float red[16 * 512];    // 32 KB
  __shared__ float rm[8], rrs[8];
  int t = threadIdx.x;
  int c0 = blockIdx.x * 64;
  int s = blockIdx.y;
  int row0 = blockIdx.z * 8;
  int kbase = s * 512;
  if (gtok) {
    for (int i = t; i < 1024; i += 256) {
      int r = i >> 7, cc = i & 127;
      int tok = gtok[r];
      ((float4*)Al)[i] = *(const float4*)(gemb + (size_t)tok * E + (cc << 2));
    }
  } else if (rpart) {
    for (int i = t; i < 1024; i += 256) {
      int r = i >> 7, cc = i & 127;
      int c = cc << 2;
      float4 v = *(const float4*)(rbias + c);
      float4 rv = *(const float4*)(rresid + (size_t)r * E + c);
      v.x += rv.x; v.y += rv.y; v.z += rv.z; v.w += rv.w;
      for (int sl = 0; sl < 4; ++sl) {
        float4 pv = *(const float4*)(rpart + ((size_t)sl * 8 + r) * E + c);
        v.x += pv.x; v.y += pv.y; v.z += pv.z; v.w += pv.w;
      }
      ((float4*)Al)[i] = v;
    }
  } else {
    for (int i = t; i < 1024; i += 256) {
      int r = i >> 7, cc = i & 127;
      ((float4*)Al)[i] = *(const float4*)(A + (size_t)(row0 + r) * K + kbase + (cc << 2));
    }
  }
  __syncthreads();
  if (lng) {
    // per-row LN of 8x512 tile (valid only when tile is the full row: K=512, kbase=0)
    int rr = t >> 5, q = t & 31;
    const float* ar = Al + rr * 512;
    float sm = 0.f, s2 = 0.f;
    for (int j = q; j < 512; j += 32) { float v = ar[j]; sm += v; s2 += v * v; }
    for (int off = 16; off; off >>= 1) {
      sm += __shfl_down(sm, off, 32);
      s2 += __shfl_down(s2, off, 32);
    }
    if (q == 0) {
      float m = sm * (1.0f / 512.0f);
      float var = s2 * (1.0f / 512.0f) - m * m;
      rm[rr] = m;
      rrs[rr] = 1.0f / sqrtf(var + 1e-5f);
    }
    __syncthreads();
    for (int idx = t; idx < 4096; idx += 256) {
      int r2 = idx >> 9, c2 = idx & 511;
      Al[idx] = (Al[idx] - rm[r2]) * rrs[r2] * lng[c2] + lnb[c2];
    }
    __syncthreads();
  }
  if (astore && blockIdx.x == 0 && blockIdx.y == 0) {
    for (int idx = t; idx < 4096; idx += 256) astore[idx] = Al[idx];
  }
  int tc = t & 15, tk = t >> 4;
  int col = c0 + (tc << 2);
  float acc[8][4];
#pragma unroll
  for (int m = 0; m < 8; ++m) { acc[m][0] = acc[m][1] = acc[m][2] = acc[m][3] = 0.f; }
  const float4* wp = (const float4*)(W + (size_t)kbase * ldw + col);
  const size_t ld4 = (size_t)(ldw >> 2);
#pragma unroll 8
  for (int i = 0; i < 32; ++i) {
    int k = tk + (i << 4);
    float4 wv = wp[(size_t)k * ld4];
#pragma unroll
    for (int m = 0; m < 8; ++m) {
      float a = Al[m * 512 + k];
      acc[m][0] += a * wv.x; acc[m][1] += a * wv.y;
      acc[m][2] += a * wv.z; acc[m][3] += a * wv.w;
    }
  }
#pragma unroll
  for (int m = 0; m < 8; ++m) {
    float4* rr2 = (float4*)&red[tk * 512 + m * 64 + (tc << 2)];
    *rr2 = make_float4(acc[m][0], acc[m][1], acc[m][2], acc[m][3]);
  }
  __syncthreads();
  float out2[2];
#pragma unroll
  for (int j = 0; j < 2; ++j) {
    int o = t + j * 256;
    float v = 0.f;
#pragma unroll
    for (int sl = 0; sl < 16; ++sl) v += red[sl * 512 + o];
    out2[j] = v;
  }
  int S = gridDim.y;
  if (S > 1) {
    int M = gridDim.z * 8;
#pragma unroll
    for (int j = 0; j < 2; ++j) {
      int o = t + j * 256; int m = o >> 6, cc = o & 63;
      C[((size_t)s * M + row0 + m) * N + c0 + cc] = out2[j];
    }
  } else {
#pragma unroll
    for (int j = 0; j < 2; ++j) {
      int o = t + j * 256; int m = o >> 6, cc = o & 63;
      int col2 = c0 + cc;
      float v = out2[j] + bias[col2];
      if (resid) v += resid[(size_t)(row0 + m) * N + col2];
      if (relu) v = fmaxf(v, 0.0f);
      C[(size_t)(row0 + m) * N + col2] = v;
      out2[j] = v;
    }
    if (amax) {
      __syncthreads();
      unsigned long long* keys = (unsigned long long*)red;
#pragma unroll
      for (int j = 0; j < 2; ++j) {
        int o = t + j * 256;
        unsigned int fb = __float_as_uint(out2[j]);
        fb = (fb & 0x80000000u) ? ~fb : (fb | 0x80000000u);
        int col2 = c0 + (o & 63);
        keys[o] = ((unsigned long long)fb << 32) |
                  (unsigned long long)(0xFFFFFFFFu - (unsigned)col2);
      }
      __syncthreads();
      if (t < 64) {
        for (int m = 0; m < 8; ++m) {
          unsigned long long k = keys[m * 64 + t];
          for (int off = 32; off; off >>= 1) {
            unsigned long long o2 = __shfl_down(k, off);
            if (o2 > k) k = o2;
          }
          if (t == 0) atomicMax(&amax[m], k);
        }
      }
    }
  }
}

// ---------------------------------------------------------------------------
// Reduce S partial slices + bias + resid (encoder FFN2). grid = M rows.
// ---------------------------------------------------------------------------
__global__ __launch_bounds__(256) void reduce_br_kernel(const float* __restrict__ part, int S, int M,
                                 const float* __restrict__ bias,
                                 const float* __restrict__ resid,
                                 float* __restrict__ outp) {
  int r = blockIdx.x, t = threadIdx.x;
#pragma unroll
  for (int j = 0; j < 2; ++j) {
    int c = t + j * 256;
    float v = bias[c] + resid[(size_t)r * E + c];
    for (int s = 0; s < S; ++s) v += part[((size_t)s * M + r) * E + c];
    outp[(size_t)r * E + c] = v;
  }
}

// ---------------------------------------------------------------------------
// Reduce S partial slices + bias + resid + LayerNorm (decoder FFN2). grid 8.
// ---------------------------------------------------------------------------
__global__ __launch_bounds__(256) void reduce_ln_kernel(const float* __restrict__ part, int S,
                                 const float* __restrict__ bias,
                                 const float* __restrict__ resid,
                                 const float* __restrict__ g, const float* __restrict__ bta,
                                 float* __restrict__ out) {
  int b = blockIdx.x, t = threadIdx.x;
  float v0 = bias[t] + resid[(size_t)b * E + t];
  float v1 = bias[t + 256] + resid[(size_t)b * E + t + 256];
  for (int s = 0; s < S; ++s) {
    v0 += part[((size_t)s * 8 + b) * E + t];
    v1 += part[((size_t)s * 8 + b) * E + t + 256];
  }
  __shared__ float red[256];
  red[t] = v0 + v1;
  __syncthreads();
  for (int s = 128; s > 0; s >>= 1) { if (t < s) red[t] += red[t + s]; __syncthreads(); }
  float m = red[0] * (1.0f / (float)E);
  __syncthreads();
  float d0 = v0 - m, d1 = v1 - m;
  red[t] = d0 * d0 + d1 * d1;
  __syncthreads();
  for (int s = 128; s > 0; s >>= 1) { if (t < s) red[t] += red[t + s]; __syncthreads(); }
  float v = red[0] * (1.0f / (float)E);
  float rstd = 1.0f / sqrtf(v + 1e-5f);
  out[(size_t)b * E + t]       = d0 * rstd * g[t]       + bta[t];
  out[(size_t)b * E + t + 256] = d1 * rstd * g[t + 256] + bta[t + 256];
}

// ---------------------------------------------------------------------------
// Encoder self-attention: block per (b,h), 256 threads.
// ---------------------------------------------------------------------------
__global__ void enc_attn_kernel(const float* __restrict__ qkv, float* __restrict__ o) {
  int b = blockIdx.x >> 3, h = blockIdx.x & 7;
  __shared__ float qs[SS * DH], ks[SS * DH], vs[SS * DH];
  __shared__ float sc[SS][SS];
  int t = threadIdx.x;
  for (int idx = t; idx < SS * DH; idx += 256) {
    int srow = idx / DH, d = idx - srow * DH;
    size_t base = ((size_t)(srow * BB + b)) * (3 * E) + h * DH + d;
    qs[idx] = qkv[base];
    ks[idx] = qkv[base + E];
    vs[idx] = qkv[base + 2 * E];
  }
  __syncthreads();
  for (int p = t; p < SS * SS; p += 256) {
    int qi = p / SS, kj = p - qi * SS;
    float a = 0.f;
    for (int d = 0; d < DH; ++d) a += qs[qi * DH + d] * ks[kj * DH + d];
    sc[qi][kj] = a * 0.125f;
  }
  __syncthreads();
  if (t < SS) {
    float mx = -1e30f;
    for (int j = 0; j < SS; ++j) mx = fmaxf(mx, sc[t][j]);
    float sm = 0.f;
    for (int j = 0; j < SS; ++j) { float ev = expf(sc[t][j] - mx); sc[t][j] = ev; sm += ev; }
    float inv = 1.0f / sm;
    for (int j = 0; j < SS; ++j) sc[t][j] *= inv;
  }
  __syncthreads();
  for (int p = t; p < SS * DH; p += 256) {
    int qi = p / DH, d = p - qi * DH;
    float a = 0.f;
    for (int j = 0; j < SS; ++j) a += sc[qi][j] * vs[j * DH + d];
    o[((size_t)(qi * BB + b)) * E + h * DH + d] = a;
  }
}

// ---------------------------------------------------------------------------
// Decoder self-attn FUSED with out-proj GEMM. grid (8,1,1), 256 threads.
// Each block redundantly computes the full (b,h) attention (cheap: <=64x24x64)
// into LDS, then does its 64-column slice of  o_sa @ W + bias + resid.
// Block 0 additionally appends K/V at `pos` to the cache.
// ---------------------------------------------------------------------------
__global__ __launch_bounds__(256) void dec_sa_ow_kernel(
    const float* __restrict__ qkv,   // [8][1536]
    float* __restrict__ Kc, float* __restrict__ Vc, int pos,
    const float* __restrict__ W,     // [512][512]
    const float* __restrict__ bias,
    const float* __restrict__ resid, // y_in [8][512]
    float* __restrict__ C) {         // y1raw [8][512]
  __shared__ float Ao[8 * 512];      // attention output tile (= A of GEMM)
  __shared__ float red[16 * 512];
  __shared__ float sc[64][25];
  int t = threadIdx.x;
  int L = pos + 1;
  if (blockIdx.x == 0) {
    for (int idx = t; idx < 4096; idx += 256) {
      int b = idx >> 9, e = idx & 511;
      const float* row = qkv + (size_t)b * 1536;
      Kc[((size_t)pos * BB + b) * E + e] = row[512 + e];
      Vc[((size_t)pos * BB + b) * E + e] = row[1024 + e];
    }
  }
  // scores: pair p = b*8+h handled by 4 threads (q = t&3)
  {
    int p = t >> 2, q = t & 3;
    int b = p >> 3, h = p & 7;
    const float4* q4 = (const float4*)(qkv + (size_t)b * 1536 + h * 64);
    for (int j = q; j < L; j += 4) {
      const float* kr = (j == pos) ? (qkv + (size_t)b * 1536 + 512 + h * 64)
                                   : (Kc + ((size_t)j * BB + b) * E + h * 64);
      const float4* k4 = (const float4*)kr;
      float a = 0.f;
#pragma unroll
      for (int d = 0; d < 16; ++d) {
        float4 qv = q4[d], kv = k4[d];
        a += qv.x * kv.x + qv.y * kv.y + qv.z * kv.z + qv.w * kv.w;
      }
      sc[p][j] = a * 0.125f;
    }
  }
  __syncthreads();
  if ((t & 3) == 0) {
    int p = t >> 2;
    float mx = -1e30f;
    for (int j = 0; j < L; ++j) mx = fmaxf(mx, sc[p][j]);
    float sm = 0.f;
    for (int j = 0; j < L; ++j) { float ev = expf(sc[p][j] - mx); sc[p][j] = ev; sm += ev; }
    float inv = 1.0f / sm;
    for (int j = 0; j < L; ++j) sc[p][j] *= inv;
  }
  __syncthreads();
  // o = P @ V  (coalesced over e)
  for (int ii = 0; ii < 16; ++ii) {
    int idx = t + (ii << 8);
    int b = idx >> 9, e = idx & 511, h = e >> 6;
    int p = b * 8 + h;
    float a = 0.f;
    for (int j = 0; j < L; ++j) {
      float vv = (j == pos) ? qkv[(size_t)b * 1536 + 1024 + e]
                            : Vc[((size_t)j * BB + b) * E + e];
      a += sc[p][j] * vv;
    }
    Ao[idx] = a;
  }
  __syncthreads();
  // GEMM slice: cols c0..c0+63
  int tc = t & 15, tk = t >> 4;
  int c0 = blockIdx.x * 64;
  int col = c0 + (tc << 2);
  float acc[8][4];
#pragma unroll
  for (int m = 0; m < 8; ++m) { acc[m][0] = acc[m][1] = acc[m][2] = acc[m][3] = 0.f; }
  const float4* wp = (const float4*)(W + col);
#pragma unroll 8
  for (int i = 0; i < 32; ++i) {
    int k = tk + (i << 4);
    float4 wv = wp[(size_t)k * 128];
#pragma unroll
    for (int m = 0; m < 8; ++m) {
      float a = Ao[m * 512 + k];
      acc[m][0] += a * wv.x; acc[m][1] += a * wv.y;
      acc[m][2] += a * wv.z; acc[m][3] += a * wv.w;
    }
  }
#pragma unroll
  for (int m = 0; m < 8; ++m) {
    float4* rr = (float4*)&red[tk * 512 + m * 64 + (tc << 2)];
    *rr = make_float4(acc[m][0], acc[m][1], acc[m][2], acc[m][3]);
  }
  __syncthreads();
#pragma unroll
  for (int j = 0; j < 2; ++j) {
    int o = t + j * 256;
    float v = 0.f;
#pragma unroll
    for (int sl = 0; sl < 16; ++sl) v += red[sl * 512 + o];
    int m = o >> 6, cc = o & 63;
    int col2 = c0 + cc;
    v += bias[col2] + resid[(size_t)m * E + col2];
    C[(size_t)m * E + col2] = v;
  }
}

// ---------------------------------------------------------------------------
// Decoder cross-attn FUSED with out-proj GEMM. grid (8,1,1), 256 threads.
// ---------------------------------------------------------------------------
__global__ __launch_bounds__(256) void dec_ca_ow_kernel(
    const float* __restrict__ qvec,  // [8][512]
    const float* __restrict__ Km, const float* __restrict__ Vm,  // [192][512]
    const float* __restrict__ W,     // [512][512]
    const float* __restrict__ bias,
    const float* __restrict__ resid, // y1 [8][512]
    float* __restrict__ C) {         // y2raw [8][512]
  __shared__ float Ao[8 * 512];
  __shared__ float red[16 * 512];
  __shared__ float sc[64][25];
  int t = threadIdx.x;
  {
    int p = t >> 2, q = t & 3;
    int b = p >> 3, h = p & 7;
    const float4* q4 = (const float4*)(qvec + (size_t)b * E + h * 64);
    for (int j = q; j < SS; j += 4) {
      const float4* k4 = (const float4*)(Km + ((size_t)j * BB + b) * E + h * 64);
      float a = 0.f;
#pragma unroll
      for (int d = 0; d < 16; ++d) {
        float4 qv = q4[d], kv = k4[d];
        a += qv.x * kv.x + qv.y * kv.y + qv.z * kv.z + qv.w * kv.w;
      }
      sc[p][j] = a * 0.125f;
    }
  }
  __syncthreads();
  if ((t & 3) == 0) {
    int p = t >> 2;
    float mx = -1e30f;
    for (int j = 0; j < SS; ++j) mx = fmaxf(mx, sc[p][j]);
    float sm = 0.f;
    for (int j = 0; j < SS; ++j) { float ev = expf(sc[p][j] - mx); sc[p][j] = ev; sm += ev; }
    float inv = 1.0f / sm;
    for (int j = 0; j < SS; ++j) sc[p][j] *= inv;
  }
  __syncthreads();
  for (int ii = 0; ii < 16; ++ii) {
    int idx = t + (ii << 8);
    int b = idx >> 9, e = idx & 511, h = e >> 6;
    int p = b * 8 + h;
    float a = 0.f;
    for (int j = 0; j < SS; ++j) a += sc[p][j] * Vm[((size_t)j * BB + b) * E + e];
    Ao[idx] = a;
  }
  __syncthreads();
  int tc = t & 15, tk = t >> 4;
  int c0 = blockIdx.x * 64;
  int col = c0 + (tc << 2);
  float acc[8][4];
#pragma unroll
  for (int m = 0; m < 8; ++m) { acc[m][0] = acc[m][1] = acc[m][2] = acc[m][3] = 0.f; }
  const float4* wp = (const float4*)(W + col);
#pragma unroll 8
  for (int i = 0; i < 32; ++i) {
    int k = tk + (i << 4);
    float4 wv = wp[(size_t)k * 128];
#pragma unroll
    for (int m = 0; m < 8; ++m) {
      float a = Ao[m * 512 + k];
      acc[m][0] += a * wv.x; acc[m][1] += a * wv.y;
      acc[m][2] += a * wv.z; acc[m][3] += a * wv.w;
    }
  }
#pragma unroll
  for (int m = 0; m < 8; ++m) {
    float4* rr = (float4*)&red[tk * 512 + m * 64 + (tc << 2)];
    *rr = make_float4(acc[m][0], acc[m][1], acc[m][2], acc[m][3]);
  }
  __syncthreads();
#pragma unroll
  for (int j = 0; j < 2; ++j) {
    int o = t + j * 256;
    float v = 0.f;
#pragma unroll
    for (int sl = 0; sl < 16; ++sl) v += red[sl * 512 + o];
    int m = o >> 6, cc = o & 63;
    int col2 = c0 + cc;
    v += bias[col2] + resid[(size_t)m * E + col2];
    C[(size_t)m * E + col2] = v;
  }
}

// ---------------------------------------------------------------------------
__global__ void dec_init_kernel(int* __restrict__ tokens, unsigned long long* __restrict__ amax) {
  int t = threadIdx.x;
  if (t < BB) { tokens[t] = START_ID; amax[t] = 0ull; }
}

__global__ void next_token_kernel(unsigned long long* __restrict__ amax, int* __restrict__ tokens,
                                  float* __restrict__ outtok, int i) {
  int t = threadIdx.x;
  if (t < BB) {
    unsigned long long p = amax[t];
    int idx = (int)(0xFFFFFFFFu - (unsigned int)(p & 0xFFFFFFFFull));
    tokens[(i + 1) * BB + t] = idx;
    outtok[i * BB + t] = (float)idx;
    amax[t] = 0ull;
  }
}

// ---------------------------------------------------------------------------
extern "C" void kernel_launch(void* const* d_in, const int* in_sizes, int n_in,
                              void* d_out, int out_size, void* d_ws, size_t ws_size,
                              hipStream_t stream) {
  (void)in_sizes; (void)n_in; (void)out_size; (void)ws_size;
  const int*   inp   = (const int*)d_in[0];
  const float* emb   = (const float*)d_in[1];
  const float* e_aw  = (const float*)d_in[2];
  const float* e_ab  = (const float*)d_in[3];
  const float* e_aow = (const float*)d_in[4];
  const float* e_aob = (const float*)d_in[5];
  const float* e_l1g = (const float*)d_in[6];
  const float* e_l1b = (const float*)d_in[7];
  const float* e_l2g = (const float*)d_in[8];
  const float* e_l2b = (const float*)d_in[9];
  const float* e_f1w = (const float*)d_in[10];
  const float* e_f1b = (const float*)d_in[11];
  const float* e_f2w = (const float*)d_in[12];
  const float* e_f2b = (const float*)d_in[13];
  const float* e_ng  = (const float*)d_in[14];
  const float* e_nb  = (const float*)d_in[15];
  const float* d_saw = (const float*)d_in[16];
  const float* d_sab = (const float*)d_in[17];
  const float* d_saow= (const float*)d_in[18];
  const float* d_saob= (const float*)d_in[19];
  const float* d_caw = (const float*)d_in[20];
  const float* d_cab = (const float*)d_in[21];
  const float* d_caow= (const float*)d_in[22];
  const float* d_caob= (const float*)d_in[23];
  const float* d_l1g = (const float*)d_in[24];
  const float* d_l1b = (const float*)d_in[25];
  const float* d_l2g = (const float*)d_in[26];
  const float* d_l2b = (const float*)d_in[27];
  const float* d_l3g = (const float*)d_in[28];
  const float* d_l3b = (const float*)d_in[29];
  const float* d_f1w = (const float*)d_in[30];
  const float* d_f1b = (const float*)d_in[31];
  const float* d_f2w = (const float*)d_in[32];
  const float* d_f2b = (const float*)d_in[33];
  const float* d_ng  = (const float*)d_in[34];
  const float* d_nb  = (const float*)d_in[35];
  const float* voc_w = (const float*)d_in[36];
  const float* voc_b = (const float*)d_in[37];
  float* out = (float*)d_out;

  // workspace carve-up (floats)
  float* p = (float*)d_ws;
  auto alloc = [&](size_t n) { float* r = p; p += n; return r; };
  float* enc_x   = alloc(192 * 512);
  float* enc_tmp = alloc(192 * 2048);
  float* enc_ao  = alloc(192 * 512);
  float* enc_raw = alloc(192 * 512);
  float* memry   = alloc(192 * 512);
  float* mem_k   = alloc(3 * 192 * 512);
  float* mem_v   = alloc(3 * 192 * 512);
  float* partE   = alloc(4 * 192 * 512);   // encoder ffn2 partials
  float* dqkv    = alloc(8 * 1536);
  float* y_in    = alloc(8 * 512);
  float* y1      = alloc(8 * 512);
  float* y1raw   = alloc(8 * 512);
  float* qca     = alloc(8 * 512);
  float* y2      = alloc(8 * 512);
  float* y2raw   = alloc(8 * 512);
  float* dmid    = alloc(8 * 2048);
  float* partD   = alloc(4 * 8 * 512);     // decoder ffn2 partials
  float* cacheK  = alloc(3 * LBUF * 8 * 512);
  float* cacheV  = alloc(3 * LBUF * 8 * 512);
  int* tokens    = (int*)alloc(LBUF * 8);
  unsigned long long* amax = (unsigned long long*)alloc(16);

#define FG_NULLS nullptr, nullptr, nullptr, nullptr, nullptr, nullptr, nullptr, nullptr

  // ---------------- encoder ----------------
  enc_embed_kernel<<<dim3(192), dim3(256), 0, stream>>>(inp, emb, enc_x);
  for (int l = 0; l < NL; ++l) {
    const float* w  = e_aw  + (size_t)l * E * 3 * E;
    const float* bq = e_ab  + (size_t)l * 3 * E;
    fgemm_kernel<<<dim3(24, 1, 24), dim3(256), 0, stream>>>(
        enc_x, E, w, 3 * E, 3 * E, bq, nullptr, enc_tmp, 0, nullptr, FG_NULLS);
    enc_attn_kernel<<<dim3(64), dim3(256), 0, stream>>>(enc_tmp, enc_ao);
    fgemm_kernel<<<dim3(8, 1, 24), dim3(256), 0, stream>>>(
        enc_ao, E, e_aow + (size_t)l * E * E, E, E, e_aob + (size_t)l * E,
        enc_x, enc_raw, 0, nullptr, FG_NULLS);
    ln_kernel<<<dim3(192), dim3(256), 0, stream>>>(enc_raw, e_l1g + l * E, e_l1b + l * E, enc_x);
    fgemm_kernel<<<dim3(32, 1, 24), dim3(256), 0, stream>>>(
        enc_x, E, e_f1w + (size_t)l * E * FF, FF, FF, e_f1b + (size_t)l * FF,
        nullptr, enc_tmp, 1, nullptr, FG_NULLS);
    fgemm_kernel<<<dim3(8, 4, 24), dim3(256), 0, stream>>>(
        enc_tmp, FF, e_f2w + (size_t)l * FF * E, E, E, nullptr,
        nullptr, partE, 0, nullptr, FG_NULLS);
    reduce_br_kernel<<<dim3(192), dim3(256), 0, stream>>>(
        partE, 4, 192, e_f2b + (size_t)l * E, enc_x, enc_raw);
    ln_kernel<<<dim3(192), dim3(256), 0, stream>>>(enc_raw, e_l2g + l * E, e_l2b + l * E, enc_x);
  }
  ln_kernel<<<dim3(192), dim3(256), 0, stream>>>(enc_x, e_ng, e_nb, memry);

  // cross-attn K,V for memory (fixed across decode steps)
  for (int l = 0; l < NL; ++l) {
    const float* w  = d_caw + (size_t)l * E * 3 * E;
    const float* bq = d_cab + (size_t)l * 3 * E;
    fgemm_kernel<<<dim3(8, 1, 24), dim3(256), 0, stream>>>(
        memry, E, w + E, 3 * E, E, bq + E, nullptr,
        mem_k + (size_t)l * 192 * 512, 0, nullptr, FG_NULLS);
    fgemm_kernel<<<dim3(8, 1, 24), dim3(256), 0, stream>>>(
        memry, E, w + 2 * E, 3 * E, E, bq + 2 * E, nullptr,
        mem_v + (size_t)l * 192 * 512, 0, nullptr, FG_NULLS);
  }

  // ---------------- greedy decode (KV-cached incremental, fused) ----------------
  dec_init_kernel<<<dim3(1), dim3(64), 0, stream>>>(tokens, amax);
  for (int i = 0; i < ML; ++i) {
    for (int l = 0; l < NL; ++l) {
      const float* saw = d_saw + (size_t)l * E * 3 * E;
      const float* sab = d_sab + (size_t)l * 3 * E;
      const float* caw = d_caw + (size_t)l * E * 3 * E;
      const float* cab = d_cab + (size_t)l * 3 * E;
      float* Kc = cacheK + (size_t)l * LBUF * 8 * 512;
      float* Vc = cacheV + (size_t)l * LBUF * 8 * 512;

      // QKV projection. l==0: fused embed gather (+store raw rows to y_in).
      // l>0: fused FFN2-reduce of previous layer + LN3 (+store y_in).
      if (l == 0) {
        fgemm_kernel<<<dim3(24, 1, 1), dim3(256), 0, stream>>>(
            nullptr, E, saw, 3 * E, 3 * E, sab, nullptr, dqkv, 0, nullptr,
            nullptr, nullptr, y_in,
            tokens + (size_t)i * BB, emb,
            nullptr, nullptr, nullptr);
      } else {
        fgemm_kernel<<<dim3(24, 1, 1), dim3(256), 0, stream>>>(
            nullptr, E, saw, 3 * E, 3 * E, sab, nullptr, dqkv, 0, nullptr,
            d_l3g + (size_t)(l - 1) * E, d_l3b + (size_t)(l - 1) * E, y_in,
            nullptr, nullptr,
            partD, d_f2b + (size_t)(l - 1) * E, y2);
      }
      // self-attn + out-proj + resid (fused)
      dec_sa_ow_kernel<<<dim3(8), dim3(256), 0, stream>>>(
          dqkv, Kc, Vc, i, d_saow + (size_t)l * E * E, d_saob + (size_t)l * E,
          y_in, y1raw);
      // LN1 (fused prologue, stores y1) + cross-attn q projection
      fgemm_kernel<<<dim3(8, 1, 1), dim3(256), 0, stream>>>(
          y1raw, E, caw, 3 * E, E, cab, nullptr, qca, 0, nullptr,
          d_l1g + (size_t)l * E, d_l1b + (size_t)l * E, y1,
          nullptr, nullptr, nullptr, nullptr, nullptr);
      // cross-attn + out-proj + resid (fused)
      dec_ca_ow_kernel<<<dim3(8), dim3(256), 0, stream>>>(
          qca, mem_k + (size_t)l * 192 * 512, mem_v + (size_t)l * 192 * 512,
          d_caow + (size_t)l * E * E, d_caob + (size_t)l * E, y1, y2raw);
      // LN2 (fused prologue, stores y2) + FFN1 + relu
      fgemm_kernel<<<dim3(32, 1, 1), dim3(256), 0, stream>>>(
          y2raw, E, d_f1w + (size_t)l * E * FF, FF, FF, d_f1b + (size_t)l * FF,
          nullptr, dmid, 1, nullptr,
          d_l2g + (size_t)l * E, d_l2b + (size_t)l * E, y2,
          nullptr, nullptr, nullptr, nullptr, nullptr);
      // FFN2 partials (k-split)
      fgemm_kernel<<<dim3(8, 4, 1), dim3(256), 0, stream>>>(
          dmid, FF, d_f2w + (size_t)l * FF * E, E, E, nullptr,
          nullptr, partD, 0, nullptr, FG_NULLS);
    }
    // last layer's FFN2 reduce + LN3 (needed before final-norm+vocab)
    reduce_ln_kernel<<<dim3(8), dim3(256), 0, stream>>>(
        partD, 4, d_f2b + (size_t)(NL - 1) * E, y2,
        d_l3g + (size_t)(NL - 1) * E, d_l3b + (size_t)(NL - 1) * E, y_in);

    float* dist_i = out + 192 + (size_t)i * (8 * VTOK);
    // final decoder norm fused into vocab GEMM prologue
    fgemm_kernel<<<dim3(500, 1, 1), dim3(256), 0, stream>>>(
        y_in, E, voc_w, VTOK, VTOK, voc_b, nullptr, dist_i, 0, amax,
        d_ng, d_nb, nullptr, nullptr, nullptr, nullptr, nullptr, nullptr);
    next_token_kernel<<<dim3(1), dim3(64), 0, stream>>>(amax, tokens, out, i);
  }
#undef FG_NULLS
}

// Round 6
// 6219.469 us; speedup vs baseline: 3.0750x; 1.4289x over previous
//
#include <hip/hip_runtime.h>
#include <stdint.h>

#define E    512
#define H    8
#define DH   64
#define BB   8
#define SS   24
#define FF   2048
#define NL   3
#define VTOK 32000
#define LBUF 25
#define ML   24
#define START_ID 1

// ---------------------------------------------------------------------------
// Encoder embedding + sinusoidal PE (double to match numpy)
// ---------------------------------------------------------------------------
__global__ void enc_embed_kernel(const int* __restrict__ inp, const float* __restrict__ emb,
                                 float* __restrict__ x) {
  int r = blockIdx.x;
  int s = r / BB, b = r % BB;
  int tok = inp[b * SS + s];
  const float* er = emb + (size_t)tok * E;
  for (int e = threadIdx.x; e < E; e += blockDim.x) {
    int j = e >> 1;
    double dv = exp(-((double)(2 * j)) * (log(10000.0) / (double)E));
    double ang = (double)s * dv;
    double pe = (e & 1) ? cos(ang) : sin(ang);
    x[(size_t)r * E + e] = er[e] + (float)pe;
  }
}

// ---------------------------------------------------------------------------
// In-place per-row LayerNorm of the block's 8x512 LDS tile.
// ---------------------------------------------------------------------------
__device__ __forceinline__ void ln_tile(float* Al, const float* __restrict__ g,
                                        const float* __restrict__ b,
                                        float* rm, float* rrs) {
  int t = threadIdx.x;
  int rr = t >> 5, q = t & 31;
  const float* ar = Al + rr * 512;
  float sm = 0.f, s2 = 0.f;
  for (int j = q; j < 512; j += 32) { float v = ar[j]; sm += v; s2 += v * v; }
  for (int off = 16; off; off >>= 1) {
    sm += __shfl_down(sm, off, 32);
    s2 += __shfl_down(s2, off, 32);
  }
  if (q == 0) {
    float m = sm * (1.0f / 512.0f);
    float var = s2 * (1.0f / 512.0f) - m * m;
    rm[rr] = m;
    rrs[rr] = 1.0f / sqrtf(var + 1e-5f);
  }
  __syncthreads();
  for (int idx = t; idx < 4096; idx += 256) {
    int r2 = idx >> 9, c2 = idx & 511;
    Al[idx] = (Al[idx] - rm[r2]) * rrs[r2] * g[c2] + b[c2];
  }
  __syncthreads();
}

// ---------------------------------------------------------------------------
// Fast GEMM: C[M,N] = A[M,K] @ W[K,N(ldw)] (+bias,resid,relu / or partials)
// grid (N/64, S, M/8), block 256.
// A-source modes:
//   gtok  != null : A rows gathered from gemb via token ids (embed fusion)
//   rpart != null : A = rbias + rresid + sum_{s<4} rpart[s]  (FFN2 reduce fusion)
//   else          : A loaded from A[M,K] at kbase
// lng  != null : per-row LN of the 8x512 A tile (requires K=512, kbase=0)
// lng2 != null : second stacked LN (encoder final: LN_l2 then LN_ng)
// astore       : blocks with (bx==0,by==0) write their post-LN tile to
//                astore + row0*512 (per-z tile; z=0-only grids unchanged)
// ---------------------------------------------------------------------------
__global__ __launch_bounds__(256) void fgemm_kernel(
    const float* __restrict__ A, int K,
    const float* __restrict__ W, int ldw, int N,
    const float* __restrict__ bias,
    const float* __restrict__ resid,
    float* __restrict__ C, int relu,
    unsigned long long* __restrict__ amax,
    const float* __restrict__ lng, const float* __restrict__ lnb,
    const float* __restrict__ lng2, const float* __restrict__ lnb2,
    float* __restrict__ astore,
    const int* __restrict__ gtok, const float* __restrict__ gemb,
    const float* __restrict__ rpart, const float* __restrict__ rbias,
    const float* __restrict__ rresid) {
  __shared__ float Al[8 * 512];      // 16 KB
  __shared__ float red[16 * 512];    // 32 KB
  __shared__ float rm[8], rrs[8];
  int t = threadIdx.x;
  int c0 = blockIdx.x * 64;
  int s = blockIdx.y;
  int row0 = blockIdx.z * 8;
  int kbase = s * 512;
  if (gtok) {
    for (int i = t; i < 1024; i += 256) {
      int r = i >> 7, cc = i & 127;
      int tok = gtok[r];
      ((float4*)Al)[i] = *(const float4*)(gemb + (size_t)tok * E + (cc << 2));
    }
  } else if (rpart) {
    for (int i = t; i < 1024; i += 256) {
      int r = i >> 7, cc = i & 127;
      int c = cc << 2;
      float4 v = *(const float4*)(rbias + c);
      float4 rv = *(const float4*)(rresid + (size_t)r * E + c);
      v.x += rv.x; v.y += rv.y; v.z += rv.z; v.w += rv.w;
      for (int sl = 0; sl < 4; ++sl) {
        float4 pv = *(const float4*)(rpart + ((size_t)sl * 8 + r) * E + c);
        v.x += pv.x; v.y += pv.y; v.z += pv.z; v.w += pv.w;
      }
      ((float4*)Al)[i] = v;
    }
  } else {
    for (int i = t; i < 1024; i += 256) {
      int r = i >> 7, cc = i & 127;
      ((float4*)Al)[i] = *(const float4*)(A + (size_t)(row0 + r) * K + kbase + (cc << 2));
    }
  }
  __syncthreads();
  if (lng) {
    ln_tile(Al, lng, lnb, rm, rrs);
    if (lng2) ln_tile(Al, lng2, lnb2, rm, rrs);
  }
  if (astore && blockIdx.x == 0 && blockIdx.y == 0) {
    float* ap = astore + (size_t)row0 * 512;
    for (int idx = t; idx < 4096; idx += 256) ap[idx] = Al[idx];
  }
  int tc = t & 15, tk = t >> 4;
  int col = c0 + (tc << 2);
  float acc[8][4];
#pragma unroll
  for (int m = 0; m < 8; ++m) { acc[m][0] = acc[m][1] = acc[m][2] = acc[m][3] = 0.f; }
  const float4* wp = (const float4*)(W + (size_t)kbase * ldw + col);
  const size_t ld4 = (size_t)(ldw >> 2);
#pragma unroll 8
  for (int i = 0; i < 32; ++i) {
    int k = tk + (i << 4);
    float4 wv = wp[(size_t)k * ld4];
#pragma unroll
    for (int m = 0; m < 8; ++m) {
      float a = Al[m * 512 + k];
      acc[m][0] += a * wv.x; acc[m][1] += a * wv.y;
      acc[m][2] += a * wv.z; acc[m][3] += a * wv.w;
    }
  }
#pragma unroll
  for (int m = 0; m < 8; ++m) {
    float4* rr2 = (float4*)&red[tk * 512 + m * 64 + (tc << 2)];
    *rr2 = make_float4(acc[m][0], acc[m][1], acc[m][2], acc[m][3]);
  }
  __syncthreads();
  float out2[2];
#pragma unroll
  for (int j = 0; j < 2; ++j) {
    int o = t + j * 256;
    float v = 0.f;
#pragma unroll
    for (int sl = 0; sl < 16; ++sl) v += red[sl * 512 + o];
    out2[j] = v;
  }
  int S = gridDim.y;
  if (S > 1) {
    int M = gridDim.z * 8;
#pragma unroll
    for (int j = 0; j < 2; ++j) {
      int o = t + j * 256; int m = o >> 6, cc = o & 63;
      C[((size_t)s * M + row0 + m) * N + c0 + cc] = out2[j];
    }
  } else {
#pragma unroll
    for (int j = 0; j < 2; ++j) {
      int o = t + j * 256; int m = o >> 6, cc = o & 63;
      int col2 = c0 + cc;
      float v = out2[j] + bias[col2];
      if (resid) v += resid[(size_t)(row0 + m) * N + col2];
      if (relu) v = fmaxf(v, 0.0f);
      C[(size_t)(row0 + m) * N + col2] = v;
      out2[j] = v;
    }
    if (amax) {
      __syncthreads();
      unsigned long long* keys = (unsigned long long*)red;
#pragma unroll
      for (int j = 0; j < 2; ++j) {
        int o = t + j * 256;
        unsigned int fb = __float_as_uint(out2[j]);
        fb = (fb & 0x80000000u) ? ~fb : (fb | 0x80000000u);
        int col2 = c0 + (o & 63);
        keys[o] = ((unsigned long long)fb << 32) |
                  (unsigned long long)(0xFFFFFFFFu - (unsigned)col2);
      }
      __syncthreads();
      if (t < 64) {
        for (int m = 0; m < 8; ++m) {
          unsigned long long k = keys[m * 64 + t];
          for (int off = 32; off; off >>= 1) {
            unsigned long long o2 = __shfl_down(k, off);
            if (o2 > k) k = o2;
          }
          if (t == 0) atomicMax(&amax[m], k);
        }
      }
    }
  }
}

// ---------------------------------------------------------------------------
// Reduce S partial slices + bias + resid (encoder FFN2). grid = M rows.
// ---------------------------------------------------------------------------
__global__ __launch_bounds__(256) void reduce_br_kernel(const float* __restrict__ part, int S, int M,
                                 const float* __restrict__ bias,
                                 const float* __restrict__ resid,
                                 float* __restrict__ outp) {
  int r = blockIdx.x, t = threadIdx.x;
#pragma unroll
  for (int j = 0; j < 2; ++j) {
    int c = t + j * 256;
    float v = bias[c] + resid[(size_t)r * E + c];
    for (int s = 0; s < S; ++s) v += part[((size_t)s * M + r) * E + c];
    outp[(size_t)r * E + c] = v;
  }
}

// ---------------------------------------------------------------------------
// Reduce S partial slices + bias + resid + LayerNorm (decoder FFN2). grid 8.
// ---------------------------------------------------------------------------
__global__ __launch_bounds__(256) void reduce_ln_kernel(const float* __restrict__ part, int S,
                                 const float* __restrict__ bias,
                                 const float* __restrict__ resid,
                                 const float* __restrict__ g, const float* __restrict__ bta,
                                 float* __restrict__ out) {
  int b = blockIdx.x, t = threadIdx.x;
  float v0 = bias[t] + resid[(size_t)b * E + t];
  float v1 = bias[t + 256] + resid[(size_t)b * E + t + 256];
  for (int s = 0; s < S; ++s) {
    v0 += part[((size_t)s * 8 + b) * E + t];
    v1 += part[((size_t)s * 8 + b) * E + t + 256];
  }
  __shared__ float red[256];
  red[t] = v0 + v1;
  __syncthreads();
  for (int s = 128; s > 0; s >>= 1) { if (t < s) red[t] += red[t + s]; __syncthreads(); }
  float m = red[0] * (1.0f / (float)E);
  __syncthreads();
  float d0 = v0 - m, d1 = v1 - m;
  red[t] = d0 * d0 + d1 * d1;
  __syncthreads();
  for (int s = 128; s > 0; s >>= 1) { if (t < s) red[t] += red[t + s]; __syncthreads(); }
  float v = red[0] * (1.0f / (float)E);
  float rstd = 1.0f / sqrtf(v + 1e-5f);
  out[(size_t)b * E + t]       = d0 * rstd * g[t]       + bta[t];
  out[(size_t)b * E + t + 256] = d1 * rstd * g[t + 256] + bta[t + 256];
}

// ---------------------------------------------------------------------------
// Encoder self-attention: block per (b,h), 256 threads.
// ---------------------------------------------------------------------------
__global__ void enc_attn_kernel(const float* __restrict__ qkv, float* __restrict__ o) {
  int b = blockIdx.x >> 3, h = blockIdx.x & 7;
  __shared__ float qs[SS * DH], ks[SS * DH], vs[SS * DH];
  __shared__ float sc[SS][SS];
  int t = threadIdx.x;
  for (int idx = t; idx < SS * DH; idx += 256) {
    int srow = idx / DH, d = idx - srow * DH;
    size_t base = ((size_t)(srow * BB + b)) * (3 * E) + h * DH + d;
    qs[idx] = qkv[base];
    ks[idx] = qkv[base + E];
    vs[idx] = qkv[base + 2 * E];
  }
  __syncthreads();
  for (int p = t; p < SS * SS; p += 256) {
    int qi = p / SS, kj = p - qi * SS;
    float a = 0.f;
    for (int d = 0; d < DH; ++d) a += qs[qi * DH + d] * ks[kj * DH + d];
    sc[qi][kj] = a * 0.125f;
  }
  __syncthreads();
  if (t < SS) {
    float mx = -1e30f;
    for (int j = 0; j < SS; ++j) mx = fmaxf(mx, sc[t][j]);
    float sm = 0.f;
    for (int j = 0; j < SS; ++j) { float ev = expf(sc[t][j] - mx); sc[t][j] = ev; sm += ev; }
    float inv = 1.0f / sm;
    for (int j = 0; j < SS; ++j) sc[t][j] *= inv;
  }
  __syncthreads();
  for (int p = t; p < SS * DH; p += 256) {
    int qi = p / DH, d = p - qi * DH;
    float a = 0.f;
    for (int j = 0; j < SS; ++j) a += sc[qi][j] * vs[j * DH + d];
    o[((size_t)(qi * BB + b)) * E + h * DH + d] = a;
  }
}

// ---------------------------------------------------------------------------
// Decoder self-attn (standalone): grid 64=(b,h), 64 threads.
// qkv row layout [b][3E]. Updates KV cache at pos, attends 0..pos.
// ---------------------------------------------------------------------------
__global__ __launch_bounds__(64) void dec_sa_attn_kernel(const float* __restrict__ qkv,
                                   float* __restrict__ Kc, float* __restrict__ Vc,
                                   float* __restrict__ o, int pos) {
  int b = blockIdx.x >> 3, h = blockIdx.x & 7;
  int t = threadIdx.x;
  const float* qp = qkv + (size_t)b * (3 * E) + h * DH;
  const float* kn = qp + E;
  const float* vn = qp + 2 * E;
  float* kc = Kc + ((size_t)pos * BB + b) * E + h * DH;
  float* vc = Vc + ((size_t)pos * BB + b) * E + h * DH;
  __shared__ float qs[DH];
  __shared__ float sc[32];
  kc[t] = kn[t]; vc[t] = vn[t]; qs[t] = qp[t];
  __syncthreads();
  int L = pos + 1;
  if (t < L) {
    const float* kr = (t == pos) ? kn : (Kc + ((size_t)t * BB + b) * E + h * DH);
    float a = 0.f;
#pragma unroll 8
    for (int d = 0; d < DH; ++d) a += qs[d] * kr[d];
    sc[t] = a * 0.125f;
  }
  __syncthreads();
  if (t == 0) {
    float mx = -1e30f;
    for (int j = 0; j < L; ++j) mx = fmaxf(mx, sc[j]);
    float sm = 0.f;
    for (int j = 0; j < L; ++j) { float ev = expf(sc[j] - mx); sc[j] = ev; sm += ev; }
    float inv = 1.0f / sm;
    for (int j = 0; j < L; ++j) sc[j] *= inv;
  }
  __syncthreads();
  float a = 0.f;
  for (int j = 0; j < L; ++j) {
    const float* vr = (j == pos) ? vn : (Vc + ((size_t)j * BB + b) * E + h * DH);
    a += sc[j] * vr[t];
  }
  o[(size_t)b * E + h * DH + t] = a;
}

// ---------------------------------------------------------------------------
// Decoder cross-attn (standalone): grid 64=(b,h), 64 threads.
// ---------------------------------------------------------------------------
__global__ __launch_bounds__(64) void dec_ca_attn_kernel(const float* __restrict__ q,
                                   const float* __restrict__ Km, const float* __restrict__ Vm,
                                   float* __restrict__ o) {
  int b = blockIdx.x >> 3, h = blockIdx.x & 7;
  int t = threadIdx.x;
  __shared__ float qs[DH];
  __shared__ float sc[SS];
  qs[t] = q[(size_t)b * E + h * DH + t];
  __syncthreads();
  if (t < SS) {
    const float* kr = Km + ((size_t)t * BB + b) * E + h * DH;
    float a = 0.f;
#pragma unroll 8
    for (int d = 0; d < DH; ++d) a += qs[d] * kr[d];
    sc[t] = a * 0.125f;
  }
  __syncthreads();
  if (t == 0) {
    float mx = -1e30f;
    for (int j = 0; j < SS; ++j) mx = fmaxf(mx, sc[j]);
    float sm = 0.f;
    for (int j = 0; j < SS; ++j) { float ev = expf(sc[j] - mx); sc[j] = ev; sm += ev; }
    float inv = 1.0f / sm;
    for (int j = 0; j < SS; ++j) sc[j] *= inv;
  }
  __syncthreads();
  float a = 0.f;
  for (int j = 0; j < SS; ++j) a += sc[j] * Vm[((size_t)j * BB + b) * E + h * DH + t];
  o[(size_t)b * E + h * DH + t] = a;
}

// ---------------------------------------------------------------------------
__global__ void dec_init_kernel(int* __restrict__ tokens, unsigned long long* __restrict__ amax) {
  int t = threadIdx.x;
  if (t < BB) { tokens[t] = START_ID; amax[t] = 0ull; }
}

__global__ void next_token_kernel(unsigned long long* __restrict__ amax, int* __restrict__ tokens,
                                  float* __restrict__ outtok, int i) {
  int t = threadIdx.x;
  if (t < BB) {
    unsigned long long p = amax[t];
    int idx = (int)(0xFFFFFFFFu - (unsigned int)(p & 0xFFFFFFFFull));
    tokens[(i + 1) * BB + t] = idx;
    outtok[i * BB + t] = (float)idx;
    amax[t] = 0ull;
  }
}

// ---------------------------------------------------------------------------
extern "C" void kernel_launch(void* const* d_in, const int* in_sizes, int n_in,
                              void* d_out, int out_size, void* d_ws, size_t ws_size,
                              hipStream_t stream) {
  (void)in_sizes; (void)n_in; (void)out_size; (void)ws_size;
  const int*   inp   = (const int*)d_in[0];
  const float* emb   = (const float*)d_in[1];
  const float* e_aw  = (const float*)d_in[2];
  const float* e_ab  = (const float*)d_in[3];
  const float* e_aow = (const float*)d_in[4];
  const float* e_aob = (const float*)d_in[5];
  const float* e_l1g = (const float*)d_in[6];
  const float* e_l1b = (const float*)d_in[7];
  const float* e_l2g = (const float*)d_in[8];
  const float* e_l2b = (const float*)d_in[9];
  const float* e_f1w = (const float*)d_in[10];
  const float* e_f1b = (const float*)d_in[11];
  const float* e_f2w = (const float*)d_in[12];
  const float* e_f2b = (const float*)d_in[13];
  const float* e_ng  = (const float*)d_in[14];
  const float* e_nb  = (const float*)d_in[15];
  const float* d_saw = (const float*)d_in[16];
  const float* d_sab = (const float*)d_in[17];
  const float* d_saow= (const float*)d_in[18];
  const float* d_saob= (const float*)d_in[19];
  const float* d_caw = (const float*)d_in[20];
  const float* d_cab = (const float*)d_in[21];
  const float* d_caow= (const float*)d_in[22];
  const float* d_caob= (const float*)d_in[23];
  const float* d_l1g = (const float*)d_in[24];
  const float* d_l1b = (const float*)d_in[25];
  const float* d_l2g = (const float*)d_in[26];
  const float* d_l2b = (const float*)d_in[27];
  const float* d_l3g = (const float*)d_in[28];
  const float* d_l3b = (const float*)d_in[29];
  const float* d_f1w = (const float*)d_in[30];
  const float* d_f1b = (const float*)d_in[31];
  const float* d_f2w = (const float*)d_in[32];
  const float* d_f2b = (const float*)d_in[33];
  const float* d_ng  = (const float*)d_in[34];
  const float* d_nb  = (const float*)d_in[35];
  const float* voc_w = (const float*)d_in[36];
  const float* voc_b = (const float*)d_in[37];
  float* out = (float*)d_out;

  // workspace carve-up (floats)
  float* p = (float*)d_ws;
  auto alloc = [&](size_t n) { float* r = p; p += n; return r; };
  float* enc_x   = alloc(192 * 512);
  float* enc_tmp = alloc(192 * 2048);
  float* enc_ao  = alloc(192 * 512);
  float* enc_raw = alloc(192 * 512);
  float* mem_k   = alloc(3 * 192 * 512);
  float* mem_v   = alloc(3 * 192 * 512);
  float* partE   = alloc(4 * 192 * 512);   // encoder ffn2 partials
  float* dqkv    = alloc(8 * 1536);
  float* y_in    = alloc(8 * 512);
  float* o_sa    = alloc(8 * 512);
  float* y1      = alloc(8 * 512);
  float* y1raw   = alloc(8 * 512);
  float* qca     = alloc(8 * 512);
  float* oca     = alloc(8 * 512);
  float* y2      = alloc(8 * 512);
  float* y2raw   = alloc(8 * 512);
  float* dmid    = alloc(8 * 2048);
  float* partD   = alloc(4 * 8 * 512);     // decoder ffn2 partials
  float* cacheK  = alloc(3 * LBUF * 8 * 512);
  float* cacheV  = alloc(3 * LBUF * 8 * 512);
  int* tokens    = (int*)alloc(LBUF * 8);
  unsigned long long* amax = (unsigned long long*)alloc(16);

// 11-null tail: amax, lng, lnb, lng2, lnb2, astore, gtok, gemb, rpart, rbias, rresid
#define FGZ nullptr, nullptr, nullptr, nullptr, nullptr, nullptr, nullptr, nullptr, nullptr, nullptr, nullptr

  // ---------------- encoder ----------------
  enc_embed_kernel<<<dim3(192), dim3(256), 0, stream>>>(inp, emb, enc_x);
  for (int l = 0; l < NL; ++l) {
    const float* w  = e_aw  + (size_t)l * E * 3 * E;
    const float* bq = e_ab  + (size_t)l * 3 * E;
    // QKV. l==0: A=enc_x (embed). l>0: A=enc_raw with fused ln2[l-1], astore enc_x.
    if (l == 0) {
      fgemm_kernel<<<dim3(24, 1, 24), dim3(256), 0, stream>>>(
          enc_x, E, w, 3 * E, 3 * E, bq, nullptr, enc_tmp, 0, FGZ);
    } else {
      fgemm_kernel<<<dim3(24, 1, 24), dim3(256), 0, stream>>>(
          enc_raw, E, w, 3 * E, 3 * E, bq, nullptr, enc_tmp, 0,
          nullptr, e_l2g + (size_t)(l - 1) * E, e_l2b + (size_t)(l - 1) * E,
          nullptr, nullptr, enc_x,
          nullptr, nullptr, nullptr, nullptr, nullptr);
    }
    enc_attn_kernel<<<dim3(64), dim3(256), 0, stream>>>(enc_tmp, enc_ao);
    fgemm_kernel<<<dim3(8, 1, 24), dim3(256), 0, stream>>>(
        enc_ao, E, e_aow + (size_t)l * E * E, E, E, e_aob + (size_t)l * E,
        enc_x, enc_raw, 0, FGZ);
    // FFN1 with fused ln1, astore enc_x (resid for reduce_br)
    fgemm_kernel<<<dim3(32, 1, 24), dim3(256), 0, stream>>>(
        enc_raw, E, e_f1w + (size_t)l * E * FF, FF, FF, e_f1b + (size_t)l * FF,
        nullptr, enc_tmp, 1,
        nullptr, e_l1g + (size_t)l * E, e_l1b + (size_t)l * E,
        nullptr, nullptr, enc_x,
        nullptr, nullptr, nullptr, nullptr, nullptr);
    fgemm_kernel<<<dim3(8, 4, 24), dim3(256), 0, stream>>>(
        enc_tmp, FF, e_f2w + (size_t)l * FF * E, E, E, nullptr,
        nullptr, partE, 0, FGZ);
    reduce_br_kernel<<<dim3(192), dim3(256), 0, stream>>>(
        partE, 4, 192, e_f2b + (size_t)l * E, enc_x, enc_raw);
  }

  // cross-attn K,V for memory: double-LN (ln2[2] then final ng) fused in prologue
  for (int l = 0; l < NL; ++l) {
    const float* w  = d_caw + (size_t)l * E * 3 * E;
    const float* bq = d_cab + (size_t)l * 3 * E;
    fgemm_kernel<<<dim3(8, 1, 24), dim3(256), 0, stream>>>(
        enc_raw, E, w + E, 3 * E, E, bq + E, nullptr,
        mem_k + (size_t)l * 192 * 512, 0,
        nullptr, e_l2g + (size_t)2 * E, e_l2b + (size_t)2 * E,
        e_ng, e_nb, nullptr,
        nullptr, nullptr, nullptr, nullptr, nullptr);
    fgemm_kernel<<<dim3(8, 1, 24), dim3(256), 0, stream>>>(
        enc_raw, E, w + 2 * E, 3 * E, E, bq + 2 * E, nullptr,
        mem_v + (size_t)l * 192 * 512, 0,
        nullptr, e_l2g + (size_t)2 * E, e_l2b + (size_t)2 * E,
        e_ng, e_nb, nullptr,
        nullptr, nullptr, nullptr, nullptr, nullptr);
  }

  // ---------------- greedy decode (KV-cached, selective fusion) ----------------
  dec_init_kernel<<<dim3(1), dim3(64), 0, stream>>>(tokens, amax);
  for (int i = 0; i < ML; ++i) {
    for (int l = 0; l < NL; ++l) {
      const float* saw = d_saw + (size_t)l * E * 3 * E;
      const float* sab = d_sab + (size_t)l * 3 * E;
      const float* caw = d_caw + (size_t)l * E * 3 * E;
      const float* cab = d_cab + (size_t)l * 3 * E;
      float* Kc = cacheK + (size_t)l * LBUF * 8 * 512;
      float* Vc = cacheV + (size_t)l * LBUF * 8 * 512;

      // QKV. l==0: fused embed gather (astore raw rows to y_in).
      // l>0: fused FFN2-reduce of previous layer + LN3 (astore y_in).
      if (l == 0) {
        fgemm_kernel<<<dim3(24, 1, 1), dim3(256), 0, stream>>>(
            nullptr, E, saw, 3 * E, 3 * E, sab, nullptr, dqkv, 0,
            nullptr, nullptr, nullptr, nullptr, nullptr, y_in,
            tokens + (size_t)i * BB, emb,
            nullptr, nullptr, nullptr);
      } else {
        fgemm_kernel<<<dim3(24, 1, 1), dim3(256), 0, stream>>>(
            nullptr, E, saw, 3 * E, 3 * E, sab, nullptr, dqkv, 0,
            nullptr, d_l3g + (size_t)(l - 1) * E, d_l3b + (size_t)(l - 1) * E,
            nullptr, nullptr, y_in,
            nullptr, nullptr,
            partD, d_f2b + (size_t)(l - 1) * E, y2);
      }
      // self-attn: standalone 64-block kernel (parallel, non-redundant)
      dec_sa_attn_kernel<<<dim3(64), dim3(64), 0, stream>>>(dqkv, Kc, Vc, o_sa, i);
      // out-proj + resid
      fgemm_kernel<<<dim3(8, 1, 1), dim3(256), 0, stream>>>(
          o_sa, E, d_saow + (size_t)l * E * E, E, E, d_saob + (size_t)l * E,
          y_in, y1raw, 0, FGZ);
      // LN1 fused into q-projection (astore y1)
      fgemm_kernel<<<dim3(8, 1, 1), dim3(256), 0, stream>>>(
          y1raw, E, caw, 3 * E, E, cab, nullptr, qca, 0,
          nullptr, d_l1g + (size_t)l * E, d_l1b + (size_t)l * E,
          nullptr, nullptr, y1,
          nullptr, nullptr, nullptr, nullptr, nullptr);
      // cross-attn: standalone 64-block kernel
      dec_ca_attn_kernel<<<dim3(64), dim3(64), 0, stream>>>(
          qca, mem_k + (size_t)l * 192 * 512, mem_v + (size_t)l * 192 * 512, oca);
      // out-proj + resid
      fgemm_kernel<<<dim3(8, 1, 1), dim3(256), 0, stream>>>(
          oca, E, d_caow + (size_t)l * E * E, E, E, d_caob + (size_t)l * E,
          y1, y2raw, 0, FGZ);
      // LN2 fused into FFN1 + relu (astore y2)
      fgemm_kernel<<<dim3(32, 1, 1), dim3(256), 0, stream>>>(
          y2raw, E, d_f1w + (size_t)l * E * FF, FF, FF, d_f1b + (size_t)l * FF,
          nullptr, dmid, 1,
          nullptr, d_l2g + (size_t)l * E, d_l2b + (size_t)l * E,
          nullptr, nullptr, y2,
          nullptr, nullptr, nullptr, nullptr, nullptr);
      // FFN2 partials (k-split)
      fgemm_kernel<<<dim3(8, 4, 1), dim3(256), 0, stream>>>(
          dmid, FF, d_f2w + (size_t)l * FF * E, E, E, nullptr,
          nullptr, partD, 0, FGZ);
    }
    // last layer's FFN2 reduce + LN3
    reduce_ln_kernel<<<dim3(8), dim3(256), 0, stream>>>(
        partD, 4, d_f2b + (size_t)(NL - 1) * E, y2,
        d_l3g + (size_t)(NL - 1) * E, d_l3b + (size_t)(NL - 1) * E, y_in);

    float* dist_i = out + 192 + (size_t)i * (8 * VTOK);
    // final decoder norm fused into vocab GEMM prologue + argmax keys
    fgemm_kernel<<<dim3(500, 1, 1), dim3(256), 0, stream>>>(
        y_in, E, voc_w, VTOK, VTOK, voc_b, nullptr, dist_i, 0,
        amax, d_ng, d_nb, nullptr, nullptr, nullptr,
        nullptr, nullptr, nullptr, nullptr, nullptr);
    next_token_kernel<<<dim3(1), dim3(64), 0, stream>>>(amax, tokens, out, i);
  }
#undef FGZ
}